// Round 13
// baseline (1000.454 us; speedup 1.0000x reference)
//
#include <hip/hip_runtime.h>

#define TT 512
#define II 8
#define HH 256
#define ST 296   // padded LDS row stride (halfs): 592B, breaks pow2 bank patterns
#define RR 8     // batch rows per block
#define NB 64    // blocks = 512 / RR
#define XSR 136  // xstage row stride in halfs

typedef _Float16 h4_t  __attribute__((ext_vector_type(4)));
typedef _Float16 h8_t  __attribute__((ext_vector_type(8)));
typedef float    f32x2 __attribute__((ext_vector_type(2)));
typedef float    f32x4 __attribute__((ext_vector_type(4)));

__device__ inline h8_t cvt8(const float* __restrict__ p, float s) {
    h8_t r;
#pragma unroll
    for (int i = 0; i < 8; ++i) r[i] = (_Float16)(p[i] * s);
    return r;
}

// DPP add (compiler-scheduled, hazard-safe). old=0, bound_ctrl=false.
template <int CTRL>
__device__ __forceinline__ float dpp_add(float v) {
    int s = __builtin_amdgcn_update_dpp(0, __builtin_bit_cast(int, v), CTRL, 0xf, 0xf, false);
    return v + __builtin_bit_cast(float, s);
}
__device__ __forceinline__ float wave_sum64(float v) {
    v = dpp_add<0x111>(v);  // row_shr:1
    v = dpp_add<0x112>(v);  // row_shr:2
    v = dpp_add<0x114>(v);  // row_shr:4
    v = dpp_add<0x118>(v);  // row_shr:8
    v = dpp_add<0x142>(v);  // row_bcast:15
    v = dpp_add<0x143>(v);  // row_bcast:31 -> lane 63 holds total
    return v;
}

// R13: N1 joins Z1 on the L2 path; last W-pool leaves LDS. R12 (735us,
// 3445 cyc/step) ledger: MFMA 2095 (invariant floor), LDS 1536 (16 b128/
// wave: 8 A + 8 N1), VALU ~1200, serial tail ~300. R12's Z1-via-L2 gained
// 248 cyc at zero cost; N1 is the same trick, made VGPR-NEUTRAL by 4-deep
// rolling double-buffers: wzv[4]+wnv[4] = 32 VGPR = exactly R12's wzv[8].
//  - first halves (s=0..3) load across the barrier (gate-tail cover ~300cyc);
//  - second halves issue at s=0..3, consumed at s=4..7 (cover ~400cyc > L2
//    latency ~200 — R10's uncovered-load bug stays fixed);
//  - wn1buf (64KB) deleted -> LDS 17.75KB; LDS b128/wave/step 16 -> 8.
// Values and chain order identical to R12-verified -> absmax must repeat.
// Tripwire: WRITE_SIZE jump above ~8MB = spill = the 32-VGPR-neutral claim
// failed -> revert to R12.
__global__ void __launch_bounds__(512, 2) gru_kernel(
    const float* __restrict__ x,    const float* __restrict__ W_ih,
    const float* __restrict__ W_hh, const float* __restrict__ b_ih,
    const float* __restrict__ b_hh, const float* __restrict__ W_lin,
    const float* __restrict__ b_lin, float* __restrict__ out,
    h8_t* __restrict__ ws)
{
    __shared__ _Float16 hbuf[2][RR][ST];    // 9.5K: h double-buffer, 8 rows
    __shared__ _Float16 xstage[2][RR][XSR]; // 4.25K: x windows
    __shared__ float predbuf[2][RR][64];    // 4K: pred ring

    const int tid  = threadIdx.x;
    const int w    = tid >> 6;     // wave 0..7
    const int lane = tid & 63;
    const int q    = lane >> 4;    // quad 0..3
    const int r15  = lane & 15;
    const int row0 = blockIdx.x * RR;

    const float sRZ = -1.44269504088896340736f;
    const float sN  =  2.88539008177792681472f;

    const int c0 = w * 32 + r15;
    const int c1 = c0 + 16;

    // ---- W_hh: R0,Z0,N0,R1 -> regs (128 AGPR); Z1,N1 -> global ws (L2) ----
    // ws layout: [g(2)][w(8)][s(8)][lane(64)] h8 = 128 KB. All blocks write
    // identical bytes (benign race, verified R10/R12).
    h8_t wfR0[8], wfZ0[8], wfN0[8], wfR1[8];
#pragma unroll
    for (int s = 0; s < 8; ++s) {
        const int k0 = s * 32 + q * 8;
        wfR0[s] = cvt8(W_hh + (size_t)(c0)       * HH + k0, sRZ);
        wfZ0[s] = cvt8(W_hh + (size_t)(256 + c0) * HH + k0, sRZ);
        wfN0[s] = cvt8(W_hh + (size_t)(512 + c0) * HH + k0, sN);
        wfR1[s] = cvt8(W_hh + (size_t)(c1)       * HH + k0, sRZ);
        ws[(size_t)((0 * 8 + w) * 8 + s) * 64 + lane] = cvt8(W_hh + (size_t)(256 + c1) * HH + k0, sRZ); // Z1
        ws[(size_t)((1 * 8 + w) * 8 + s) * 64 + lane] = cvt8(W_hh + (size_t)(512 + c1) * HH + k0, sN);  // N1
    }
    // ---- x-part B-fragments over [x(8)|bias(1)|0..] ----
    h4_t xfR[2], xfZ[2], xfN[2];
#pragma unroll
    for (int g = 0; g < 2; ++g) {
        const int cR = g ? c1 : c0;
#pragma unroll
        for (int j = 0; j < 4; ++j) {
            const int kp = q * 4 + j;
            float vR = 0.f, vZ = 0.f, vN = 0.f;
            if (kp < 8) {
                vR = W_ih[(cR)       * II + kp] * sRZ;
                vZ = W_ih[(256 + cR) * II + kp] * sRZ;
                vN = W_ih[(512 + cR) * II + kp] * sN;
            } else if (kp == 8) {
                vR = (b_ih[cR]       + b_hh[cR])       * sRZ;
                vZ = (b_ih[256 + cR] + b_hh[256 + cR]) * sRZ;
                vN = b_ih[512 + cR] * sN;
            }
            xfR[g][j] = (_Float16)vR; xfZ[g][j] = (_Float16)vZ; xfN[g][j] = (_Float16)vN;
        }
    }
    const bool hi = (lane >= 32);
    const float bhnp = (hi ? b_hh[512 + c1] : b_hh[512 + c0]) * sN;
    const float blin = b_lin[0];
    const float wl0 = W_lin[lane * 4 + 0], wl1 = W_lin[lane * 4 + 1];
    const float wl2 = W_lin[lane * 4 + 2], wl3 = W_lin[lane * 4 + 3];

    const h4_t bias4 = {(_Float16)1.f, (_Float16)0.f, (_Float16)0.f, (_Float16)0.f};
    const h4_t zero4 = {(_Float16)0.f, (_Float16)0.f, (_Float16)0.f, (_Float16)0.f};

    // ---- LDS init + x window 0 preload ----
    for (int i = tid; i < 2 * RR * ST; i += 512) (&hbuf[0][0][0])[i] = (_Float16)0.f;
    const int xrow = tid >> 6, xf2 = (tid & 63) * 2;
    {
        const f32x2 v = *(const f32x2*)(x + (size_t)(row0 + xrow) * TT * II + xf2);
        xstage[0][xrow][xf2]     = (_Float16)v[0];
        xstage[0][xrow][xf2 + 1] = (_Float16)v[1];
    }
    __syncthreads();   // drains vmcnt(0): ws writes complete before first read

    const h8_t* __restrict__ wz_g = ws + (size_t)((0 * 8 + w) * 8) * 64 + lane;  // Z1, L2
    const h8_t* __restrict__ wn_g = ws + (size_t)((1 * 8 + w) * 8) * 64 + lane;  // N1, L2

    // prologue: first halves (s=0..3) of both streams
    h8_t wzv[4], wnv[4];
#pragma unroll
    for (int s = 0; s < 4; ++s) { wzv[s] = wz_g[s * 64]; wnv[s] = wn_g[s * 64]; }

    f32x4 hreg = {0.f, 0.f, 0.f, 0.f};
    const f32x4 z4 = {0.f, 0.f, 0.f, 0.f};

    const int rb   = (q & 1) * 4;
    const int colp = hi ? c1 : c0;
    const int ar   = r15 & 7;          // aliased A-row (rows 8-15 -> 0-7)

    // hoisted pointer pairs (selected by compile-time ti&1 after unroll)
    const _Float16* __restrict__ hbA0 = &hbuf[0][ar][0];
    const _Float16* __restrict__ hbA1 = &hbuf[1][ar][0];
    const _Float16* __restrict__ pr0  = &hbuf[0][w][lane * 4];
    const _Float16* __restrict__ pr1  = &hbuf[1][w][lane * 4];
    _Float16* __restrict__ hw0 = &hbuf[0][rb][colp];
    _Float16* __restrict__ hw1 = &hbuf[1][rb][colp];
    const _Float16* __restrict__ xsl0 = &xstage[0][ar][(q & 1) * 4];
    const _Float16* __restrict__ xsl1 = &xstage[1][ar][(q & 1) * 4];
    _Float16* __restrict__ xw0 = &xstage[0][xrow][xf2];
    _Float16* __restrict__ xw1 = &xstage[1][xrow][xf2];
    const float* __restrict__ xrp = x + ((size_t)(row0 + xrow) * TT + 16) * II + xf2;

    for (int tw = 0; tw < 32; ++tw) {
        const _Float16* __restrict__ xs_rd = (tw & 1) ? xsl1 : xsl0;
        _Float16* __restrict__ xs_wr = (tw & 1) ? xw0 : xw1;   // other buffer

        // window refill: one load, consumed at ti==15
        f32x2 xpre = {0.f, 0.f};
        if (tw < 31) xpre = *(const f32x2*)xrp;

#pragma unroll
        for (int ti = 0; ti < 16; ++ti) {
            const int t = tw * 16 + ti;
            const int cur = ti & 1;

            const _Float16* __restrict__ hb = cur ? hbA1 : hbA0;
            const h4_t xa = *(const h4_t*)(xs_rd + ti * 8);
            const h4_t a2 = (q < 2) ? xa : ((q == 2) ? bias4 : zero4);
            f32x4 accR0 = __builtin_amdgcn_mfma_f32_16x16x16f16(a2, xfR[0], z4, 0, 0, 0);
            f32x4 accZ0 = __builtin_amdgcn_mfma_f32_16x16x16f16(a2, xfZ[0], z4, 0, 0, 0);
            f32x4 gin0  = __builtin_amdgcn_mfma_f32_16x16x16f16(a2, xfN[0], z4, 0, 0, 0);
            f32x4 accR1 = __builtin_amdgcn_mfma_f32_16x16x16f16(a2, xfR[1], z4, 0, 0, 0);
            f32x4 accZ1 = __builtin_amdgcn_mfma_f32_16x16x16f16(a2, xfZ[1], z4, 0, 0, 0);
            f32x4 gin1  = __builtin_amdgcn_mfma_f32_16x16x16f16(a2, xfN[1], z4, 0, 0, 0);
            f32x4 accN0 = z4, accN1 = z4;
            // fused 6-chain interleave; Z1/N1 from 4-deep rolling L2 buffers:
            // slots 0..3 hold s (first half, loaded across the barrier) then
            // get refilled with s+4 while s runs (cover ~4 iters > L2 lat).
#pragma unroll
            for (int s = 0; s < 8; ++s) {
                const h8_t a  = *(const h8_t*)(hb + s * 32 + q * 8);
                const h8_t wz = wzv[s & 3];
                const h8_t wn = wnv[s & 3];
                if (s < 4) {   // issue second-half refill for slot s
                    wzv[s] = wz_g[(s + 4) * 64];
                    wnv[s] = wn_g[(s + 4) * 64];
                }
                accR0 = __builtin_amdgcn_mfma_f32_16x16x32_f16(a, wfR0[s], accR0, 0, 0, 0);
                accZ0 = __builtin_amdgcn_mfma_f32_16x16x32_f16(a, wfZ0[s], accZ0, 0, 0, 0);
                accN0 = __builtin_amdgcn_mfma_f32_16x16x32_f16(a, wfN0[s], accN0, 0, 0, 0);
                accR1 = __builtin_amdgcn_mfma_f32_16x16x32_f16(a, wfR1[s], accR1, 0, 0, 0);
                accZ1 = __builtin_amdgcn_mfma_f32_16x16x32_f16(a, wz,      accZ1, 0, 0, 0);
                accN1 = __builtin_amdgcn_mfma_f32_16x16x32_f16(a, wn,      accN1, 0, 0, 0);
            }

            // reissue first halves for the NEXT step: gate tail (~300cyc)
            // covers L2 latency; barrier vmcnt(0) drain then costs ~0.
#pragma unroll
            for (int s = 0; s < 4; ++s) { wzv[s] = wz_g[s * 64]; wnv[s] = wn_g[s * 64]; }

            // pred_{t-1} (VALU-only DPP reduce; reads stable hbuf[cur])
            if (t > 0) {
                const h4_t hv4 = *(const h4_t*)(cur ? pr1 : pr0);
                float s0 = (float)hv4[0] * wl0 + (float)hv4[1] * wl1
                         + (float)hv4[2] * wl2 + (float)hv4[3] * wl3;
                s0 = wave_sum64(s0);
                if (lane == 63) predbuf[((t - 1) >> 6) & 1][w][(t - 1) & 63] = s0 + blin;
            }

            // gate tail, dense packed (lanes 0-31 g0, 32-63 g1); no mirror
            _Float16* __restrict__ hw = cur ? hw0 : hw1;   // write buf nxt=cur^1
#pragma unroll
            for (int j = 0; j < 4; ++j) {
                const float vR = hi ? accR1[j] : accR0[j];
                const float vZ = hi ? accZ1[j] : accZ0[j];
                const float vN = hi ? accN1[j] : accN0[j];
                const float vG = hi ? gin1[j]  : gin0[j];
                const float rr = __builtin_amdgcn_rcpf(1.f + __builtin_amdgcn_exp2f(vR));
                const float zz = __builtin_amdgcn_rcpf(1.f + __builtin_amdgcn_exp2f(vZ));
                const float u  = vG + rr * (vN + bhnp);
                const float nn = 1.f - 2.f * __builtin_amdgcn_rcpf(1.f + __builtin_amdgcn_exp2f(u));
                const float hv = nn + zz * (hreg[j] - nn);
                hreg[j] = hv;
                hw[j * ST] = (_Float16)hv;
            }

            // x window writeback (load issued at tw start; vmcnt hidden)
            if (ti == 15 && tw < 31) {
                xs_wr[0] = (_Float16)xpre[0];
                xs_wr[1] = (_Float16)xpre[1];
            }

            __syncthreads();   // single barrier per step

            // coalesced pred flush: one 2KB store per 64 steps
            if (ti == 0 && (tw & 3) == 0 && tw > 0) {
                const int pb = ((t >> 6) & 1) ^ 1;
                out[(size_t)(row0 + (tid >> 6)) * TT + (t - 64) + (tid & 63)] =
                    predbuf[pb][tid >> 6][tid & 63];
            }
        }
        xrp += 16 * II;
    }

    // final pred for t = TT-1 (h_final in hbuf[0])
    {
        const h4_t hv4 = *(const h4_t*)pr0;
        float s0 = (float)hv4[0] * wl0 + (float)hv4[1] * wl1
                 + (float)hv4[2] * wl2 + (float)hv4[3] * wl3;
        s0 = wave_sum64(s0);
        if (lane == 63) predbuf[1][w][63] = s0 + blin;
    }
    __syncthreads();
    // flush last chunk [448, 512)
    out[(size_t)(row0 + (tid >> 6)) * TT + 448 + (tid & 63)] =
        predbuf[1][tid >> 6][tid & 63];
}

extern "C" void kernel_launch(void* const* d_in, const int* in_sizes, int n_in,
                              void* d_out, int out_size, void* d_ws, size_t ws_size,
                              hipStream_t stream) {
    const float* x     = (const float*)d_in[0];
    const float* W_ih  = (const float*)d_in[1];
    const float* W_hh  = (const float*)d_in[2];
    const float* b_ih  = (const float*)d_in[3];
    const float* b_hh  = (const float*)d_in[4];
    const float* W_lin = (const float*)d_in[5];
    const float* b_lin = (const float*)d_in[6];
    float* out = (float*)d_out;
    // ws: 2*8*8*64 h8 fragments = 128 KiB (Z1 + N1 W pools, L2-resident)
    gru_kernel<<<NB, 512, 0, stream>>>(x, W_ih, W_hh, b_ih, b_hh, W_lin, b_lin, out,
                                       (h8_t*)d_ws);
}

// Round 14
// 892.286 us; speedup vs baseline: 1.1212x; 1.1212x over previous
//
#include <hip/hip_runtime.h>

#define TT 512
#define II 8
#define HH 256
#define ST 296   // padded LDS row stride (halfs): 592B, breaks pow2 bank patterns
#define RR 8     // batch rows per block
#define NB 64    // blocks = 512 / RR
#define XSR 136  // xstage row stride in halfs

typedef _Float16 h4_t  __attribute__((ext_vector_type(4)));
typedef _Float16 h8_t  __attribute__((ext_vector_type(8)));
typedef float    f32x2 __attribute__((ext_vector_type(2)));
typedef float    f32x4 __attribute__((ext_vector_type(4)));

__device__ inline h8_t cvt8(const float* __restrict__ p, float s) {
    h8_t r;
#pragma unroll
    for (int i = 0; i < 8; ++i) r[i] = (_Float16)(p[i] * s);
    return r;
}

// DPP add (compiler-scheduled, hazard-safe). old=0, bound_ctrl=false.
template <int CTRL>
__device__ __forceinline__ float dpp_add(float v) {
    int s = __builtin_amdgcn_update_dpp(0, __builtin_bit_cast(int, v), CTRL, 0xf, 0xf, false);
    return v + __builtin_bit_cast(float, s);
}
__device__ __forceinline__ float wave_sum64(float v) {
    v = dpp_add<0x111>(v);  // row_shr:1
    v = dpp_add<0x112>(v);  // row_shr:2
    v = dpp_add<0x114>(v);  // row_shr:4
    v = dpp_add<0x118>(v);  // row_shr:8
    v = dpp_add<0x142>(v);  // row_bcast:15
    v = dpp_add<0x143>(v);  // row_bcast:31 -> lane 63 holds total
    return v;
}

// R14: revert to verified R12 (735us) + s_setprio around the MFMA cluster.
// R13's tripwire fired (970us): its WRITE_SIZE delta was the doubled ws
// init (not spill); the real cost was (a) 16 b128 loads/wave on the L1/TA
// path (~16 cyc each to move 1KB vs ~12 on LDS) and (b) mid-MFMA-loop
// refills injecting vmcnt waits into the fused 6-chain schedule
// (MfmaUtil 12.9 -> 9.6). Rule: ONE pool via L2-across-the-barrier = win
// (R12); two pools or mid-loop refill = loss (R10/R13). L2 lever exhausted.
// The one addition: our 2 waves/SIMD are phase-offset within a step (one
// in the MFMA cluster while the other runs gate tail/pred) -> T5 setprio
// role-diversity regime; worth 0..+5%, correctness-neutral.
// LDS: 9.5K hbuf + 64K wn1buf + 4.25K xstage + 4K predbuf = 81.7K.
__global__ void __launch_bounds__(512, 2) gru_kernel(
    const float* __restrict__ x,    const float* __restrict__ W_ih,
    const float* __restrict__ W_hh, const float* __restrict__ b_ih,
    const float* __restrict__ b_hh, const float* __restrict__ W_lin,
    const float* __restrict__ b_lin, float* __restrict__ out,
    h8_t* __restrict__ ws)
{
    __shared__ _Float16 hbuf[2][RR][ST];    // 9.5K: h double-buffer, 8 rows
    __shared__ h8_t wn1buf[8 * 8 * 64];     // 64K: N1 W frags, lane-private
    __shared__ _Float16 xstage[2][RR][XSR]; // 4.25K: x windows
    __shared__ float predbuf[2][RR][64];    // 4K: pred ring

    const int tid  = threadIdx.x;
    const int w    = tid >> 6;     // wave 0..7
    const int lane = tid & 63;
    const int q    = lane >> 4;    // quad 0..3
    const int r15  = lane & 15;
    const int row0 = blockIdx.x * RR;

    const float sRZ = -1.44269504088896340736f;
    const float sN  =  2.88539008177792681472f;

    const int c0 = w * 32 + r15;
    const int c1 = c0 + 16;

    // ---- W_hh: R0,Z0,N0,R1 -> regs (128 AGPR); Z1 -> global ws; N1 -> LDS ----
    h8_t wfR0[8], wfZ0[8], wfN0[8], wfR1[8];
#pragma unroll
    for (int s = 0; s < 8; ++s) {
        const int k0 = s * 32 + q * 8;
        wfR0[s] = cvt8(W_hh + (size_t)(c0)       * HH + k0, sRZ);
        wfZ0[s] = cvt8(W_hh + (size_t)(256 + c0) * HH + k0, sRZ);
        wfN0[s] = cvt8(W_hh + (size_t)(512 + c0) * HH + k0, sN);
        wfR1[s] = cvt8(W_hh + (size_t)(c1)       * HH + k0, sRZ);
        ws[(size_t)(w * 8 + s) * 64 + lane] = cvt8(W_hh + (size_t)(256 + c1) * HH + k0, sRZ); // Z1
        wn1buf[(w * 8 + s) * 64 + lane]     = cvt8(W_hh + (size_t)(512 + c1) * HH + k0, sN);  // N1
    }
    // ---- x-part B-fragments over [x(8)|bias(1)|0..] ----
    h4_t xfR[2], xfZ[2], xfN[2];
#pragma unroll
    for (int g = 0; g < 2; ++g) {
        const int cR = g ? c1 : c0;
#pragma unroll
        for (int j = 0; j < 4; ++j) {
            const int kp = q * 4 + j;
            float vR = 0.f, vZ = 0.f, vN = 0.f;
            if (kp < 8) {
                vR = W_ih[(cR)       * II + kp] * sRZ;
                vZ = W_ih[(256 + cR) * II + kp] * sRZ;
                vN = W_ih[(512 + cR) * II + kp] * sN;
            } else if (kp == 8) {
                vR = (b_ih[cR]       + b_hh[cR])       * sRZ;
                vZ = (b_ih[256 + cR] + b_hh[256 + cR]) * sRZ;
                vN = b_ih[512 + cR] * sN;
            }
            xfR[g][j] = (_Float16)vR; xfZ[g][j] = (_Float16)vZ; xfN[g][j] = (_Float16)vN;
        }
    }
    const bool hi = (lane >= 32);
    const float bhnp = (hi ? b_hh[512 + c1] : b_hh[512 + c0]) * sN;
    const float blin = b_lin[0];
    const float wl0 = W_lin[lane * 4 + 0], wl1 = W_lin[lane * 4 + 1];
    const float wl2 = W_lin[lane * 4 + 2], wl3 = W_lin[lane * 4 + 3];

    const h4_t bias4 = {(_Float16)1.f, (_Float16)0.f, (_Float16)0.f, (_Float16)0.f};
    const h4_t zero4 = {(_Float16)0.f, (_Float16)0.f, (_Float16)0.f, (_Float16)0.f};

    // ---- LDS init + x window 0 preload ----
    for (int i = tid; i < 2 * RR * ST; i += 512) (&hbuf[0][0][0])[i] = (_Float16)0.f;
    const int xrow = tid >> 6, xf2 = (tid & 63) * 2;
    {
        const f32x2 v = *(const f32x2*)(x + (size_t)(row0 + xrow) * TT * II + xf2);
        xstage[0][xrow][xf2]     = (_Float16)v[0];
        xstage[0][xrow][xf2 + 1] = (_Float16)v[1];
    }
    __syncthreads();   // drains vmcnt(0): ws writes complete before first read

    const h8_t* __restrict__ wz_g = ws + (size_t)(w * 8) * 64 + lane;   // L2
    const h8_t* __restrict__ wn_l = &wn1buf[w * 8 * 64 + lane];         // LDS

    // prologue: first wzv fill (L2-hot after the ws writes)
    h8_t wzv[8];
#pragma unroll
    for (int s = 0; s < 8; ++s) wzv[s] = wz_g[s * 64];

    f32x4 hreg = {0.f, 0.f, 0.f, 0.f};
    const f32x4 z4 = {0.f, 0.f, 0.f, 0.f};

    const int rb   = (q & 1) * 4;
    const int colp = hi ? c1 : c0;
    const int ar   = r15 & 7;          // aliased A-row (rows 8-15 -> 0-7)

    // hoisted pointer pairs (selected by compile-time ti&1 after unroll)
    const _Float16* __restrict__ hbA0 = &hbuf[0][ar][0];
    const _Float16* __restrict__ hbA1 = &hbuf[1][ar][0];
    const _Float16* __restrict__ pr0  = &hbuf[0][w][lane * 4];
    const _Float16* __restrict__ pr1  = &hbuf[1][w][lane * 4];
    _Float16* __restrict__ hw0 = &hbuf[0][rb][colp];
    _Float16* __restrict__ hw1 = &hbuf[1][rb][colp];
    const _Float16* __restrict__ xsl0 = &xstage[0][ar][(q & 1) * 4];
    const _Float16* __restrict__ xsl1 = &xstage[1][ar][(q & 1) * 4];
    _Float16* __restrict__ xw0 = &xstage[0][xrow][xf2];
    _Float16* __restrict__ xw1 = &xstage[1][xrow][xf2];
    const float* __restrict__ xrp = x + ((size_t)(row0 + xrow) * TT + 16) * II + xf2;

    for (int tw = 0; tw < 32; ++tw) {
        const _Float16* __restrict__ xs_rd = (tw & 1) ? xsl1 : xsl0;
        _Float16* __restrict__ xs_wr = (tw & 1) ? xw0 : xw1;   // other buffer

        // window refill: one load, consumed at ti==15
        f32x2 xpre = {0.f, 0.f};
        if (tw < 31) xpre = *(const f32x2*)xrp;

#pragma unroll
        for (int ti = 0; ti < 16; ++ti) {
            const int t = tw * 16 + ti;
            const int cur = ti & 1;

            const _Float16* __restrict__ hb = cur ? hbA1 : hbA0;
            const h4_t xa = *(const h4_t*)(xs_rd + ti * 8);
            const h4_t a2 = (q < 2) ? xa : ((q == 2) ? bias4 : zero4);

            __builtin_amdgcn_s_setprio(1);   // favor this wave through the MFMA cluster
            f32x4 accR0 = __builtin_amdgcn_mfma_f32_16x16x16f16(a2, xfR[0], z4, 0, 0, 0);
            f32x4 accZ0 = __builtin_amdgcn_mfma_f32_16x16x16f16(a2, xfZ[0], z4, 0, 0, 0);
            f32x4 gin0  = __builtin_amdgcn_mfma_f32_16x16x16f16(a2, xfN[0], z4, 0, 0, 0);
            f32x4 accR1 = __builtin_amdgcn_mfma_f32_16x16x16f16(a2, xfR[1], z4, 0, 0, 0);
            f32x4 accZ1 = __builtin_amdgcn_mfma_f32_16x16x16f16(a2, xfZ[1], z4, 0, 0, 0);
            f32x4 gin1  = __builtin_amdgcn_mfma_f32_16x16x16f16(a2, xfN[1], z4, 0, 0, 0);
            f32x4 accN0 = z4, accN1 = z4;
            // fused 6-chain interleave (R9 structure); Z1 from wzv regs
            // (loaded LAST step; barrier already drained vmcnt -> no wait)
#pragma unroll
            for (int s = 0; s < 8; ++s) {
                const h8_t a  = *(const h8_t*)(hb + s * 32 + q * 8);
                const h8_t wn = wn_l[s * 64];
                accR0 = __builtin_amdgcn_mfma_f32_16x16x32_f16(a, wfR0[s], accR0, 0, 0, 0);
                accZ0 = __builtin_amdgcn_mfma_f32_16x16x32_f16(a, wfZ0[s], accZ0, 0, 0, 0);
                accN0 = __builtin_amdgcn_mfma_f32_16x16x32_f16(a, wfN0[s], accN0, 0, 0, 0);
                accR1 = __builtin_amdgcn_mfma_f32_16x16x32_f16(a, wfR1[s], accR1, 0, 0, 0);
                accZ1 = __builtin_amdgcn_mfma_f32_16x16x32_f16(a, wzv[s],  accZ1, 0, 0, 0);
                accN1 = __builtin_amdgcn_mfma_f32_16x16x32_f16(a, wn,      accN1, 0, 0, 0);
            }
            __builtin_amdgcn_s_setprio(0);

            // reissue Z1 loads for the NEXT step: gate tail (~300cyc) covers
            // L2 latency; barrier vmcnt(0) drain then costs ~0. The barrier
            // fence prevents CSE/sinking of these loads.
#pragma unroll
            for (int s = 0; s < 8; ++s) wzv[s] = wz_g[s * 64];

            // pred_{t-1} (VALU-only DPP reduce; reads stable hbuf[cur])
            if (t > 0) {
                const h4_t hv4 = *(const h4_t*)(cur ? pr1 : pr0);
                float s0 = (float)hv4[0] * wl0 + (float)hv4[1] * wl1
                         + (float)hv4[2] * wl2 + (float)hv4[3] * wl3;
                s0 = wave_sum64(s0);
                if (lane == 63) predbuf[((t - 1) >> 6) & 1][w][(t - 1) & 63] = s0 + blin;
            }

            // gate tail, dense packed (lanes 0-31 g0, 32-63 g1); no mirror
            _Float16* __restrict__ hw = cur ? hw0 : hw1;   // write buf nxt=cur^1
#pragma unroll
            for (int j = 0; j < 4; ++j) {
                const float vR = hi ? accR1[j] : accR0[j];
                const float vZ = hi ? accZ1[j] : accZ0[j];
                const float vN = hi ? accN1[j] : accN0[j];
                const float vG = hi ? gin1[j]  : gin0[j];
                const float rr = __builtin_amdgcn_rcpf(1.f + __builtin_amdgcn_exp2f(vR));
                const float zz = __builtin_amdgcn_rcpf(1.f + __builtin_amdgcn_exp2f(vZ));
                const float u  = vG + rr * (vN + bhnp);
                const float nn = 1.f - 2.f * __builtin_amdgcn_rcpf(1.f + __builtin_amdgcn_exp2f(u));
                const float hv = nn + zz * (hreg[j] - nn);
                hreg[j] = hv;
                hw[j * ST] = (_Float16)hv;
            }

            // x window writeback (load issued at tw start; vmcnt hidden)
            if (ti == 15 && tw < 31) {
                xs_wr[0] = (_Float16)xpre[0];
                xs_wr[1] = (_Float16)xpre[1];
            }

            __syncthreads();   // single barrier per step

            // coalesced pred flush: one 2KB store per 64 steps
            if (ti == 0 && (tw & 3) == 0 && tw > 0) {
                const int pb = ((t >> 6) & 1) ^ 1;
                out[(size_t)(row0 + (tid >> 6)) * TT + (t - 64) + (tid & 63)] =
                    predbuf[pb][tid >> 6][tid & 63];
            }
        }
        xrp += 16 * II;
    }

    // final pred for t = TT-1 (h_final in hbuf[0])
    {
        const h4_t hv4 = *(const h4_t*)pr0;
        float s0 = (float)hv4[0] * wl0 + (float)hv4[1] * wl1
                 + (float)hv4[2] * wl2 + (float)hv4[3] * wl3;
        s0 = wave_sum64(s0);
        if (lane == 63) predbuf[1][w][63] = s0 + blin;
    }
    __syncthreads();
    // flush last chunk [448, 512)
    out[(size_t)(row0 + (tid >> 6)) * TT + 448 + (tid & 63)] =
        predbuf[1][tid >> 6][tid & 63];
}

extern "C" void kernel_launch(void* const* d_in, const int* in_sizes, int n_in,
                              void* d_out, int out_size, void* d_ws, size_t ws_size,
                              hipStream_t stream) {
    const float* x     = (const float*)d_in[0];
    const float* W_ih  = (const float*)d_in[1];
    const float* W_hh  = (const float*)d_in[2];
    const float* b_ih  = (const float*)d_in[3];
    const float* b_hh  = (const float*)d_in[4];
    const float* W_lin = (const float*)d_in[5];
    const float* b_lin = (const float*)d_in[6];
    float* out = (float*)d_out;
    // ws: 8*8*64 h8 fragments = 64 KiB (Z1 W pool, L2-resident)
    gru_kernel<<<NB, 512, 0, stream>>>(x, W_ih, W_hh, b_ih, b_hh, W_lin, b_lin, out,
                                       (h8_t*)d_ws);
}

// Round 15
// 762.111 us; speedup vs baseline: 1.3127x; 1.1708x over previous
//
#include <hip/hip_runtime.h>

#define TT 512
#define II 8
#define HH 256
#define ST 296   // padded LDS row stride (halfs): 592B, breaks pow2 bank patterns
#define RR 8     // batch rows per block
#define NB 64    // blocks = 512 / RR
#define XSR 136  // xstage row stride in halfs

typedef _Float16 h4_t  __attribute__((ext_vector_type(4)));
typedef _Float16 h8_t  __attribute__((ext_vector_type(8)));
typedef float    f32x2 __attribute__((ext_vector_type(2)));
typedef float    f32x4 __attribute__((ext_vector_type(4)));

__device__ inline h8_t cvt8(const float* __restrict__ p, float s) {
    h8_t r;
#pragma unroll
    for (int i = 0; i < 8; ++i) r[i] = (_Float16)(p[i] * s);
    return r;
}

// DPP add (compiler-scheduled, hazard-safe). old=0, bound_ctrl=false.
template <int CTRL>
__device__ __forceinline__ float dpp_add(float v) {
    int s = __builtin_amdgcn_update_dpp(0, __builtin_bit_cast(int, v), CTRL, 0xf, 0xf, false);
    return v + __builtin_bit_cast(float, s);
}
__device__ __forceinline__ float wave_sum64(float v) {
    v = dpp_add<0x111>(v);  // row_shr:1
    v = dpp_add<0x112>(v);  // row_shr:2
    v = dpp_add<0x114>(v);  // row_shr:4
    v = dpp_add<0x118>(v);  // row_shr:8
    v = dpp_add<0x142>(v);  // row_bcast:15
    v = dpp_add<0x143>(v);  // row_bcast:31 -> lane 63 holds total
    return v;
}

// R15: EXACT revert to R12 (verified 735us). R14's setprio cost -18%:
// our 8 waves are barrier-lockstep per step (m190's negative regime, not
// m191's) — raising MFMA-cluster prio starves the gate-tail wave everyone
// then waits for at the barrier (MfmaUtil 12.9->10.8, WRITE_SIZE +2.5MB).
// R13's second-L2-pool cost -32% (L1/TA path + mid-loop vmcnt breaks the
// fused schedule). Ledger at R12: step = 3445 cyc; MFMA-issue floor 2095
// cyc/SIMD (invariant under any RR/block decomposition — duplication waste
// cancels CU-spread); gap = A/N1 LDS stream + data-dependent gate tail +
// barrier skew. Eviction levers each exhausted: AGPRs full (4 chains),
// ONE L2 pool optimal (Z1, across-the-barrier), DPP pred, full unroll.
// LDS: 9.5K hbuf + 64K wn1buf + 4.25K xstage + 4K predbuf = 81.7K.
__global__ void __launch_bounds__(512, 2) gru_kernel(
    const float* __restrict__ x,    const float* __restrict__ W_ih,
    const float* __restrict__ W_hh, const float* __restrict__ b_ih,
    const float* __restrict__ b_hh, const float* __restrict__ W_lin,
    const float* __restrict__ b_lin, float* __restrict__ out,
    h8_t* __restrict__ ws)
{
    __shared__ _Float16 hbuf[2][RR][ST];    // 9.5K: h double-buffer, 8 rows
    __shared__ h8_t wn1buf[8 * 8 * 64];     // 64K: N1 W frags, lane-private
    __shared__ _Float16 xstage[2][RR][XSR]; // 4.25K: x windows
    __shared__ float predbuf[2][RR][64];    // 4K: pred ring

    const int tid  = threadIdx.x;
    const int w    = tid >> 6;     // wave 0..7
    const int lane = tid & 63;
    const int q    = lane >> 4;    // quad 0..3
    const int r15  = lane & 15;
    const int row0 = blockIdx.x * RR;

    const float sRZ = -1.44269504088896340736f;
    const float sN  =  2.88539008177792681472f;

    const int c0 = w * 32 + r15;
    const int c1 = c0 + 16;

    // ---- W_hh: R0,Z0,N0,R1 -> regs (128 AGPR); Z1 -> global ws; N1 -> LDS ----
    h8_t wfR0[8], wfZ0[8], wfN0[8], wfR1[8];
#pragma unroll
    for (int s = 0; s < 8; ++s) {
        const int k0 = s * 32 + q * 8;
        wfR0[s] = cvt8(W_hh + (size_t)(c0)       * HH + k0, sRZ);
        wfZ0[s] = cvt8(W_hh + (size_t)(256 + c0) * HH + k0, sRZ);
        wfN0[s] = cvt8(W_hh + (size_t)(512 + c0) * HH + k0, sN);
        wfR1[s] = cvt8(W_hh + (size_t)(c1)       * HH + k0, sRZ);
        ws[(size_t)(w * 8 + s) * 64 + lane] = cvt8(W_hh + (size_t)(256 + c1) * HH + k0, sRZ); // Z1
        wn1buf[(w * 8 + s) * 64 + lane]     = cvt8(W_hh + (size_t)(512 + c1) * HH + k0, sN);  // N1
    }
    // ---- x-part B-fragments over [x(8)|bias(1)|0..] ----
    h4_t xfR[2], xfZ[2], xfN[2];
#pragma unroll
    for (int g = 0; g < 2; ++g) {
        const int cR = g ? c1 : c0;
#pragma unroll
        for (int j = 0; j < 4; ++j) {
            const int kp = q * 4 + j;
            float vR = 0.f, vZ = 0.f, vN = 0.f;
            if (kp < 8) {
                vR = W_ih[(cR)       * II + kp] * sRZ;
                vZ = W_ih[(256 + cR) * II + kp] * sRZ;
                vN = W_ih[(512 + cR) * II + kp] * sN;
            } else if (kp == 8) {
                vR = (b_ih[cR]       + b_hh[cR])       * sRZ;
                vZ = (b_ih[256 + cR] + b_hh[256 + cR]) * sRZ;
                vN = b_ih[512 + cR] * sN;
            }
            xfR[g][j] = (_Float16)vR; xfZ[g][j] = (_Float16)vZ; xfN[g][j] = (_Float16)vN;
        }
    }
    const bool hi = (lane >= 32);
    const float bhnp = (hi ? b_hh[512 + c1] : b_hh[512 + c0]) * sN;
    const float blin = b_lin[0];
    const float wl0 = W_lin[lane * 4 + 0], wl1 = W_lin[lane * 4 + 1];
    const float wl2 = W_lin[lane * 4 + 2], wl3 = W_lin[lane * 4 + 3];

    const h4_t bias4 = {(_Float16)1.f, (_Float16)0.f, (_Float16)0.f, (_Float16)0.f};
    const h4_t zero4 = {(_Float16)0.f, (_Float16)0.f, (_Float16)0.f, (_Float16)0.f};

    // ---- LDS init + x window 0 preload ----
    for (int i = tid; i < 2 * RR * ST; i += 512) (&hbuf[0][0][0])[i] = (_Float16)0.f;
    const int xrow = tid >> 6, xf2 = (tid & 63) * 2;
    {
        const f32x2 v = *(const f32x2*)(x + (size_t)(row0 + xrow) * TT * II + xf2);
        xstage[0][xrow][xf2]     = (_Float16)v[0];
        xstage[0][xrow][xf2 + 1] = (_Float16)v[1];
    }
    __syncthreads();   // drains vmcnt(0): ws writes complete before first read

    const h8_t* __restrict__ wz_g = ws + (size_t)(w * 8) * 64 + lane;   // L2
    const h8_t* __restrict__ wn_l = &wn1buf[w * 8 * 64 + lane];         // LDS

    // prologue: first wzv fill (L2-hot after the ws writes)
    h8_t wzv[8];
#pragma unroll
    for (int s = 0; s < 8; ++s) wzv[s] = wz_g[s * 64];

    f32x4 hreg = {0.f, 0.f, 0.f, 0.f};
    const f32x4 z4 = {0.f, 0.f, 0.f, 0.f};

    const int rb   = (q & 1) * 4;
    const int colp = hi ? c1 : c0;
    const int ar   = r15 & 7;          // aliased A-row (rows 8-15 -> 0-7)

    // hoisted pointer pairs (selected by compile-time ti&1 after unroll)
    const _Float16* __restrict__ hbA0 = &hbuf[0][ar][0];
    const _Float16* __restrict__ hbA1 = &hbuf[1][ar][0];
    const _Float16* __restrict__ pr0  = &hbuf[0][w][lane * 4];
    const _Float16* __restrict__ pr1  = &hbuf[1][w][lane * 4];
    _Float16* __restrict__ hw0 = &hbuf[0][rb][colp];
    _Float16* __restrict__ hw1 = &hbuf[1][rb][colp];
    const _Float16* __restrict__ xsl0 = &xstage[0][ar][(q & 1) * 4];
    const _Float16* __restrict__ xsl1 = &xstage[1][ar][(q & 1) * 4];
    _Float16* __restrict__ xw0 = &xstage[0][xrow][xf2];
    _Float16* __restrict__ xw1 = &xstage[1][xrow][xf2];
    const float* __restrict__ xrp = x + ((size_t)(row0 + xrow) * TT + 16) * II + xf2;

    for (int tw = 0; tw < 32; ++tw) {
        const _Float16* __restrict__ xs_rd = (tw & 1) ? xsl1 : xsl0;
        _Float16* __restrict__ xs_wr = (tw & 1) ? xw0 : xw1;   // other buffer

        // window refill: one load, consumed at ti==15
        f32x2 xpre = {0.f, 0.f};
        if (tw < 31) xpre = *(const f32x2*)xrp;

#pragma unroll
        for (int ti = 0; ti < 16; ++ti) {
            const int t = tw * 16 + ti;
            const int cur = ti & 1;

            const _Float16* __restrict__ hb = cur ? hbA1 : hbA0;
            const h4_t xa = *(const h4_t*)(xs_rd + ti * 8);
            const h4_t a2 = (q < 2) ? xa : ((q == 2) ? bias4 : zero4);
            f32x4 accR0 = __builtin_amdgcn_mfma_f32_16x16x16f16(a2, xfR[0], z4, 0, 0, 0);
            f32x4 accZ0 = __builtin_amdgcn_mfma_f32_16x16x16f16(a2, xfZ[0], z4, 0, 0, 0);
            f32x4 gin0  = __builtin_amdgcn_mfma_f32_16x16x16f16(a2, xfN[0], z4, 0, 0, 0);
            f32x4 accR1 = __builtin_amdgcn_mfma_f32_16x16x16f16(a2, xfR[1], z4, 0, 0, 0);
            f32x4 accZ1 = __builtin_amdgcn_mfma_f32_16x16x16f16(a2, xfZ[1], z4, 0, 0, 0);
            f32x4 gin1  = __builtin_amdgcn_mfma_f32_16x16x16f16(a2, xfN[1], z4, 0, 0, 0);
            f32x4 accN0 = z4, accN1 = z4;
            // fused 6-chain interleave (R9 structure); Z1 from wzv regs
            // (loaded LAST step; barrier already drained vmcnt -> no wait)
#pragma unroll
            for (int s = 0; s < 8; ++s) {
                const h8_t a  = *(const h8_t*)(hb + s * 32 + q * 8);
                const h8_t wn = wn_l[s * 64];
                accR0 = __builtin_amdgcn_mfma_f32_16x16x32_f16(a, wfR0[s], accR0, 0, 0, 0);
                accZ0 = __builtin_amdgcn_mfma_f32_16x16x32_f16(a, wfZ0[s], accZ0, 0, 0, 0);
                accN0 = __builtin_amdgcn_mfma_f32_16x16x32_f16(a, wfN0[s], accN0, 0, 0, 0);
                accR1 = __builtin_amdgcn_mfma_f32_16x16x32_f16(a, wfR1[s], accR1, 0, 0, 0);
                accZ1 = __builtin_amdgcn_mfma_f32_16x16x32_f16(a, wzv[s],  accZ1, 0, 0, 0);
                accN1 = __builtin_amdgcn_mfma_f32_16x16x32_f16(a, wn,      accN1, 0, 0, 0);
            }

            // reissue Z1 loads for the NEXT step: gate tail (~300cyc) covers
            // L2 latency; barrier vmcnt(0) drain then costs ~0. The barrier
            // fence prevents CSE/sinking of these loads.
#pragma unroll
            for (int s = 0; s < 8; ++s) wzv[s] = wz_g[s * 64];

            // pred_{t-1} (VALU-only DPP reduce; reads stable hbuf[cur])
            if (t > 0) {
                const h4_t hv4 = *(const h4_t*)(cur ? pr1 : pr0);
                float s0 = (float)hv4[0] * wl0 + (float)hv4[1] * wl1
                         + (float)hv4[2] * wl2 + (float)hv4[3] * wl3;
                s0 = wave_sum64(s0);
                if (lane == 63) predbuf[((t - 1) >> 6) & 1][w][(t - 1) & 63] = s0 + blin;
            }

            // gate tail, dense packed (lanes 0-31 g0, 32-63 g1); no mirror
            _Float16* __restrict__ hw = cur ? hw0 : hw1;   // write buf nxt=cur^1
#pragma unroll
            for (int j = 0; j < 4; ++j) {
                const float vR = hi ? accR1[j] : accR0[j];
                const float vZ = hi ? accZ1[j] : accZ0[j];
                const float vN = hi ? accN1[j] : accN0[j];
                const float vG = hi ? gin1[j]  : gin0[j];
                const float rr = __builtin_amdgcn_rcpf(1.f + __builtin_amdgcn_exp2f(vR));
                const float zz = __builtin_amdgcn_rcpf(1.f + __builtin_amdgcn_exp2f(vZ));
                const float u  = vG + rr * (vN + bhnp);
                const float nn = 1.f - 2.f * __builtin_amdgcn_rcpf(1.f + __builtin_amdgcn_exp2f(u));
                const float hv = nn + zz * (hreg[j] - nn);
                hreg[j] = hv;
                hw[j * ST] = (_Float16)hv;
            }

            // x window writeback (load issued at tw start; vmcnt hidden)
            if (ti == 15 && tw < 31) {
                xs_wr[0] = (_Float16)xpre[0];
                xs_wr[1] = (_Float16)xpre[1];
            }

            __syncthreads();   // single barrier per step

            // coalesced pred flush: one 2KB store per 64 steps
            if (ti == 0 && (tw & 3) == 0 && tw > 0) {
                const int pb = ((t >> 6) & 1) ^ 1;
                out[(size_t)(row0 + (tid >> 6)) * TT + (t - 64) + (tid & 63)] =
                    predbuf[pb][tid >> 6][tid & 63];
            }
        }
        xrp += 16 * II;
    }

    // final pred for t = TT-1 (h_final in hbuf[0])
    {
        const h4_t hv4 = *(const h4_t*)pr0;
        float s0 = (float)hv4[0] * wl0 + (float)hv4[1] * wl1
                 + (float)hv4[2] * wl2 + (float)hv4[3] * wl3;
        s0 = wave_sum64(s0);
        if (lane == 63) predbuf[1][w][63] = s0 + blin;
    }
    __syncthreads();
    // flush last chunk [448, 512)
    out[(size_t)(row0 + (tid >> 6)) * TT + 448 + (tid & 63)] =
        predbuf[1][tid >> 6][tid & 63];
}

extern "C" void kernel_launch(void* const* d_in, const int* in_sizes, int n_in,
                              void* d_out, int out_size, void* d_ws, size_t ws_size,
                              hipStream_t stream) {
    const float* x     = (const float*)d_in[0];
    const float* W_ih  = (const float*)d_in[1];
    const float* W_hh  = (const float*)d_in[2];
    const float* b_ih  = (const float*)d_in[3];
    const float* b_hh  = (const float*)d_in[4];
    const float* W_lin = (const float*)d_in[5];
    const float* b_lin = (const float*)d_in[6];
    float* out = (float*)d_out;
    // ws: 8*8*64 h8 fragments = 64 KiB (Z1 W pool, L2-resident)
    gru_kernel<<<NB, 512, 0, stream>>>(x, W_ih, W_hh, b_ih, b_hh, W_lin, b_lin, out,
                                       (h8_t*)d_ws);
}